// Round 7
// baseline (120.304 us; speedup 1.0000x reference)
//
#include <hip/hip_runtime.h>
#include <cstdint>
#include <cstddef>

#define E_DIM 1024
#define PD 64            // proj dim
#define NP 128           // 2*proj dim
#define B_DIM 8
#define S_DIM 2048
#define M_TOT (B_DIM * S_DIM)   // 16384

#define BMR 128          // rows per block
#define SPLITK 4
#define KQ (E_DIM / SPLITK)  // 256
#define BK 32
#define NCH (KQ / BK)        // 8 chunks

__device__ __forceinline__ void gload16(const float* g, float* l) {
    __builtin_amdgcn_global_load_lds(
        (const __attribute__((address_space(1))) unsigned int*)g,
        (__attribute__((address_space(3))) unsigned int*)(uintptr_t)l,
        16, 0, 0);
}

// ---------------- K1: split-K(4) GEMM partials (no bias) ----------------
// qkP[m][p] = sum_{k in quarter} A[m][k]*W[p][k];  A = context as (S*B,E), m = s*B+b.
// 256 thr, per-thread 8 rows x 8 cols (FMA/LDS-byte = 1.0 -> LDS/VALU balanced).
// Staging via global_load_lds, linear LDS [row][32], source granule pre-XORed with
// key = (row>>3)&7 so reads at slot (g ^ (row>>3))&7 spread all bank groups:
//  - A-read (fixed i,g): 4 distinct rows/wave, 4 distinct granule groups -> conflict-free
//  - B-read (fixed c,g): 16 distinct rows, 8 granule groups x2 -> 2-way (free)
__global__ __launch_bounds__(256, 2) void gemm_qk(const float* __restrict__ A,
                                                  const float* __restrict__ W,
                                                  float* __restrict__ qk0,
                                                  float* __restrict__ qk1,
                                                  float* __restrict__ qk2,
                                                  float* __restrict__ qk3) {
    __shared__ float As[2][BMR][BK];   // 16 KB x2
    __shared__ float Bs[2][NP][BK];    // 16 KB x2  (total 64 KB)
    const int tid = threadIdx.x;
    const int kh  = blockIdx.x & 3;
    const int m0  = (blockIdx.x >> 2) * BMR;
    const int k0  = kh * KQ;
    const int w   = __builtin_amdgcn_readfirstlane(tid >> 6);  // wave id (uniform)
    const int ln  = tid & 63;
    const int tyr = tid >> 4;       // 0..15 -> rows tyr*8..+7
    const int txc = tid & 15;       // 0..15 -> cols txc*8..+7
    const int g8  = ln & 7;         // staging slot granule
    const int lr  = ln >> 3;        // staging row within 8-row group

    float* qkP = (kh == 0) ? qk0 : (kh == 1) ? qk1 : (kh == 2) ? qk2 : qk3;

    const float* aRow = A + (size_t)(m0 + w * 32 + lr) * E_DIM + k0;
    const float* bRow = W + (size_t)(w * 32 + lr) * E_DIM + k0;

    float acc[8][8];
#pragma unroll
    for (int i = 0; i < 8; ++i)
#pragma unroll
        for (int c = 0; c < 8; ++c) acc[i][c] = 0.f;

#define STAGE(BUF, KOFF)                                                          \
    {                                                                             \
        _Pragma("unroll")                                                         \
        for (int j = 0; j < 4; ++j) {                                             \
            const int key = (w * 4 + j) & 7;                                      \
            const int sx = ((g8 ^ key) << 2);                                     \
            gload16(aRow + (size_t)j * 8 * E_DIM + (KOFF) + sx,                   \
                    &As[BUF][w * 32 + j * 8][0]);                                 \
            gload16(bRow + (size_t)j * 8 * E_DIM + (KOFF) + sx,                   \
                    &Bs[BUF][w * 32 + j * 8][0]);                                 \
        }                                                                         \
    }

    STAGE(0, 0)

    for (int ch = 0; ch < NCH; ++ch) {
        const int buf = ch & 1;
        __syncthreads();   // compiler drains vmcnt before barrier -> staged data valid
        if (ch + 1 < NCH) {
            const int nb = buf ^ 1;
            STAGE(nb, (ch + 1) * BK)
        }
#pragma unroll
        for (int g = 0; g < 8; ++g) {
            float b_[8][4];
#pragma unroll
            for (int c = 0; c < 8; ++c) {
                const float4 v = *(const float4*)&Bs[buf][txc * 8 + c][((g ^ txc) & 7) << 2];
                b_[c][0] = v.x; b_[c][1] = v.y; b_[c][2] = v.z; b_[c][3] = v.w;
            }
#pragma unroll
            for (int i = 0; i < 8; ++i) {
                const float4 av = *(const float4*)&As[buf][tyr * 8 + i][((g ^ tyr) & 7) << 2];
#pragma unroll
                for (int c = 0; c < 8; ++c) {
                    acc[i][c] += av.x * b_[c][0];
                    acc[i][c] += av.y * b_[c][1];
                    acc[i][c] += av.z * b_[c][2];
                    acc[i][c] += av.w * b_[c][3];
                }
            }
        }
    }

#pragma unroll
    for (int i = 0; i < 8; ++i) {
        const size_t m = (size_t)(m0 + tyr * 8 + i);
        float4 o0, o1;
        o0.x = acc[i][0]; o0.y = acc[i][1]; o0.z = acc[i][2]; o0.w = acc[i][3];
        o1.x = acc[i][4]; o1.y = acc[i][5]; o1.z = acc[i][6]; o1.w = acc[i][7];
        *(float4*)&qkP[m * NP + txc * 8] = o0;
        *(float4*)&qkP[m * NP + txc * 8 + 4] = o1;
    }
#undef STAGE
}

// ---------------- K2: sum 4 partials + bias, neighbor scores, 2-way softmax ----------------
__global__ __launch_bounds__(256) void neighbor_probs(const float* __restrict__ qk0,
                                                      const float* __restrict__ qk1,
                                                      const float* __restrict__ qk2,
                                                      const float* __restrict__ qk3,
                                                      const float* __restrict__ bias,
                                                      float* __restrict__ p0,
                                                      float* __restrict__ p1) {
    const int m = blockIdx.x * 4 + (threadIdx.x >> 6);  // position index m = s*B+b
    const int lane = threadIdx.x & 63;
    const int s = m >> 3;   // / B_DIM
    const int b = m & 7;    // % B_DIM

    const float bq = bias[lane];
    const float bk = bias[PD + lane];
    const size_t oq = (size_t)m * NP + lane;
    const float q = qk0[oq] + qk1[oq] + qk2[oq] + qk3[oq] + bq;
    float kn = 0.f, kp = 0.f;
    if (s < S_DIM - 1) {
        const size_t o = (size_t)(m + B_DIM) * NP + PD + lane;
        kn = qk0[o] + qk1[o] + qk2[o] + qk3[o] + bk;
    }
    if (s > 0) {
        const size_t o = (size_t)(m - B_DIM) * NP + PD + lane;
        kp = qk0[o] + qk1[o] + qk2[o] + qk3[o] + bk;
    }
    float f = q * kn;   // fwd partial: query[s] . key[s+1]
    float g = q * kp;   // bwd partial: query[s] . key[s-1]
#pragma unroll
    for (int off = 32; off; off >>= 1) {
        f += __shfl_xor(f, off);
        g += __shfl_xor(g, off);
    }
    if (lane == 0) {
        const float s0 = f * (1.f / (float)E_DIM);
        const float s1 = g * (1.f / (float)E_DIM);
        float P0, P1;
        if (s == S_DIM - 1) { P0 = 0.f; P1 = 1.f; }
        else if (s == 0)    { P0 = 1.f; P1 = 0.f; }
        else {
            const float mx = fmaxf(s0, s1);
            const float e0 = __expf(s0 - mx), e1 = __expf(s1 - mx);
            const float inv = 1.f / (e0 + e1);
            P0 = e0 * inv; P1 = e1 * inv;
        }
        p0[b * S_DIM + s] = P0;
        p1[b * S_DIM + s] = P1;
    }
}

// ---------------- K3: combine (flat roll), neighbor_attn out, log, exclusive scan ----------------
__global__ __launch_bounds__(256) void combine_scan(const float* __restrict__ p0,
                                                    const float* __restrict__ p1,
                                                    const float* __restrict__ prior,
                                                    float* __restrict__ out_na,
                                                    float* __restrict__ cs) {
    const int b = blockIdx.x;
    const int tid = threadIdx.x;
    __shared__ float sh[256];

    const int base = b * S_DIM + tid * 8;
    float incl[8];
    float run = 0.f;
#pragma unroll
    for (int u = 0; u < 8; ++u) {
        const int fidx = base + u;
        int nf = fidx + 1;
        if (nf == B_DIM * S_DIM) nf = 0;   // torch .roll on flattened tensor wraps globally
        const float P0 = p0[fidx];
        const float sp = p1[nf];
        const float pr = prior[fidx];
        const float na = pr + (1.f - pr) * sqrtf(P0 * sp + 1e-6f);
        out_na[fidx] = na;
        run += __logf(na);
        incl[u] = run;
    }
    sh[tid] = run;
    __syncthreads();
    for (int off = 1; off < 256; off <<= 1) {
        float v = sh[tid];
        if (tid >= off) v += sh[tid - off];
        __syncthreads();
        sh[tid] = v;
        __syncthreads();
    }
    const float offset = (tid > 0) ? sh[tid - 1] : 0.f;
#pragma unroll
    for (int u = 0; u < 8; ++u) {
        cs[base + u] = offset + ((u > 0) ? incl[u - 1] : 0.f);  // exclusive prefix
    }
}

// ---------------- K4: big output C[b,i,j] = exp(sign*(cs[j]-cs[i])), 0 on diag ----------------
__global__ __launch_bounds__(256) void big_out(const float* __restrict__ cs,
                                               float* __restrict__ out) {
    const int bi = blockIdx.x;          // b*S + i
    const int b = bi >> 11;             // / S_DIM
    const int i = bi & (S_DIM - 1);
    const float ci = cs[b * S_DIM + i];
    const float* crow = cs + (size_t)b * S_DIM;
    float* orow = out + (size_t)bi * S_DIM;
    const int j0 = threadIdx.x * 8;
#pragma unroll
    for (int h = 0; h < 2; ++h) {
        const int j = j0 + h * 4;
        const float4 cj = *(const float4*)&crow[j];
        float4 o;
        {
            const int jj = j + 0; const float m = (jj > i) ? (cj.x - ci) : (ci - cj.x);
            o.x = (jj == i) ? 0.f : __expf(m);
        }
        {
            const int jj = j + 1; const float m = (jj > i) ? (cj.y - ci) : (ci - cj.y);
            o.y = (jj == i) ? 0.f : __expf(m);
        }
        {
            const int jj = j + 2; const float m = (jj > i) ? (cj.z - ci) : (ci - cj.z);
            o.z = (jj == i) ? 0.f : __expf(m);
        }
        {
            const int jj = j + 3; const float m = (jj > i) ? (cj.w - ci) : (ci - cj.w);
            o.w = (jj == i) ? 0.f : __expf(m);
        }
        *(float4*)&orow[j] = o;
    }
}

extern "C" void kernel_launch(void* const* d_in, const int* in_sizes, int n_in,
                              void* d_out, int out_size, void* d_ws, size_t ws_size,
                              hipStream_t stream) {
    const float* context = (const float*)d_in[0];   // (S,B,E) fp32
    const float* prior   = (const float*)d_in[1];   // (B,S) fp32
    const float* W       = (const float*)d_in[2];   // (128,1024) fp32
    const float* bias    = (const float*)d_in[3];   // (128,) fp32
    float* out = (float*)d_out;

    float* qk0 = (float*)d_ws;                         // 16384*128 floats (8 MB)
    float* p0  = qk0 + (size_t)M_TOT * NP;             // 16384 floats
    float* p1  = p0 + M_TOT;                           // 16384 floats
    float* cs  = p1 + M_TOT;                           // 16384 floats
    // partials 1..3 live in d_out's C-region (134 MB); K4 overwrites afterwards
    float* qk1 = out;
    float* qk2 = out + (size_t)M_TOT * NP;
    float* qk3 = out + (size_t)2 * M_TOT * NP;
    float* na_out = out + (size_t)B_DIM * S_DIM * S_DIM;  // second output

    gemm_qk<<<(M_TOT / BMR) * SPLITK, 256, 0, stream>>>(context, W, qk0, qk1, qk2, qk3);
    neighbor_probs<<<M_TOT / 4, 256, 0, stream>>>(qk0, qk1, qk2, qk3, bias, p0, p1);
    combine_scan<<<B_DIM, 256, 0, stream>>>(p0, p1, prior, na_out, cs);
    big_out<<<M_TOT, 256, 0, stream>>>(cs, out);
}

// Round 8
// 66.617 us; speedup vs baseline: 1.8059x; 1.8059x over previous
//
#include <hip/hip_runtime.h>
#include <cstdint>
#include <cstddef>

#define E_DIM 1024
#define PD 64            // proj dim
#define NP 128           // 2*proj dim
#define B_DIM 8
#define S_DIM 2048
#define M_TOT (B_DIM * S_DIM)   // 16384

#define KH 512           // K per split-half
#define BM 64            // rows per block
#define BK 32
#define NCH (KH / BK)    // 16 chunks per half

typedef __attribute__((ext_vector_type(8))) short short8v;  // 8 bf16 (4 VGPR)
typedef __attribute__((ext_vector_type(4))) float f32x4;    // MFMA acc

__device__ __forceinline__ void gload16(const float* g, float* l) {
    __builtin_amdgcn_global_load_lds(
        (const __attribute__((address_space(1))) unsigned int*)g,
        (__attribute__((address_space(3))) unsigned int*)(uintptr_t)l,
        16, 0, 0);
}

// two-fold split: a = hi + lo exactly at the fp32->bf16 boundary (truncation split;
// lo captures hi's truncation error; residual ~2^-16 relative)
__device__ __forceinline__ void cvt_hilo(const f32x4 v0, const f32x4 v1,
                                         short8v& h, short8v& l) {
    const unsigned MSK = 0xFFFF0000u;
    unsigned a0 = __float_as_uint(v0.x), a1 = __float_as_uint(v0.y);
    unsigned a2 = __float_as_uint(v0.z), a3 = __float_as_uint(v0.w);
    unsigned a4 = __float_as_uint(v1.x), a5 = __float_as_uint(v1.y);
    unsigned a6 = __float_as_uint(v1.z), a7 = __float_as_uint(v1.w);
    float l0 = v0.x - __uint_as_float(a0 & MSK);
    float l1 = v0.y - __uint_as_float(a1 & MSK);
    float l2 = v0.z - __uint_as_float(a2 & MSK);
    float l3 = v0.w - __uint_as_float(a3 & MSK);
    float l4 = v1.x - __uint_as_float(a4 & MSK);
    float l5 = v1.y - __uint_as_float(a5 & MSK);
    float l6 = v1.z - __uint_as_float(a6 & MSK);
    float l7 = v1.w - __uint_as_float(a7 & MSK);
    union { unsigned u[4]; short8v s; } H, L;
    H.u[0] = (a1 & MSK) | (a0 >> 16);
    H.u[1] = (a3 & MSK) | (a2 >> 16);
    H.u[2] = (a5 & MSK) | (a4 >> 16);
    H.u[3] = (a7 & MSK) | (a6 >> 16);
    L.u[0] = (__float_as_uint(l1) & MSK) | (__float_as_uint(l0) >> 16);
    L.u[1] = (__float_as_uint(l3) & MSK) | (__float_as_uint(l2) >> 16);
    L.u[2] = (__float_as_uint(l5) & MSK) | (__float_as_uint(l4) >> 16);
    L.u[3] = (__float_as_uint(l7) & MSK) | (__float_as_uint(l6) >> 16);
    h = H.s; l = L.s;
}

// ---------------- K1: split-K(2) bf16-MFMA GEMM partials (no bias) ----------------
// qkP[m][p] = sum_{k in half} A[m][k]*W[p][k];  A = context as (S*B,E), m = s*B+b.
// 256 thr = 4 waves (2x2 grid of 32x64 wave tiles); 16x16x32 bf16 MFMA, hi/lo split
// (3 MFMA per frag pair). Staging via global_load_lds into linear [row][32] fp32
// tiles, source granule pre-XORed with key=(row&7) so frag reads (16 consecutive
// rows at fixed k-granule) spread evenly over all 8 bank-quads.
__global__ __launch_bounds__(256, 2) void gemm_qk(const float* __restrict__ A,
                                                  const float* __restrict__ W,
                                                  float* __restrict__ qk0,
                                                  float* __restrict__ qk1) {
    __shared__ float As[2][BM][BK];    // 8 KB x2
    __shared__ float Ws[2][NP][BK];    // 16 KB x2  (48 KB total)
    const int tid = threadIdx.x;
    const int kh  = blockIdx.x & 1;
    const int m0  = (blockIdx.x >> 1) * BM;
    const int k0  = kh * KH;
    const int w   = __builtin_amdgcn_readfirstlane(tid >> 6);  // wave id (uniform)
    const int ln  = tid & 63;

    // staging mapping: issue j covers 8 LDS rows; lane -> row lr, slot granule ln&7,
    // global granule (ln&7)^lr (so slot s at row r holds logical granule s^(r&7))
    const int lr   = ln >> 3;
    const int gsrc = ((ln & 7) ^ lr) << 2;                     // floats
    const float* aS = A + (size_t)(m0 + w * 16 + lr) * E_DIM + k0 + gsrc;
    const float* wS = W + (size_t)(w * 32 + lr) * E_DIM + k0 + gsrc;

    // compute mapping
    const int row16 = ln & 15;        // frag row/col index
    const int kq    = ln >> 4;        // k-quadrant: k = kq*8..+7
    const int wm    = (w >> 1) * 32;  // wave row base
    const int wn    = (w & 1) * 64;   // wave col base
    const int sg0   = (((kq << 1) | 0) ^ (row16 & 7)) << 2;    // slot offsets (floats)
    const int sg1   = (((kq << 1) | 1) ^ (row16 & 7)) << 2;

    float* qkP = kh ? qk1 : qk0;

    f32x4 acc[2][4];
#pragma unroll
    for (int i = 0; i < 2; ++i)
#pragma unroll
        for (int j = 0; j < 4; ++j) acc[i][j] = (f32x4){0.f, 0.f, 0.f, 0.f};

#define STAGE(BUF, KOFF)                                                       \
    {                                                                          \
        gload16(aS + (KOFF),               &As[BUF][w * 16][0]);               \
        gload16(aS + (KOFF) + 8 * E_DIM,   &As[BUF][w * 16 + 8][0]);           \
        gload16(wS + (KOFF),               &Ws[BUF][w * 32][0]);               \
        gload16(wS + (KOFF) + 8 * E_DIM,   &Ws[BUF][w * 32 + 8][0]);           \
        gload16(wS + (KOFF) + 16 * E_DIM,  &Ws[BUF][w * 32 + 16][0]);          \
        gload16(wS + (KOFF) + 24 * E_DIM,  &Ws[BUF][w * 32 + 24][0]);          \
    }

    STAGE(0, 0)

    for (int ch = 0; ch < NCH; ++ch) {
        const int buf = ch & 1;
        __syncthreads();   // drains vmcnt before barrier -> staged chunk valid
        if (ch + 1 < NCH) {
            STAGE(buf ^ 1, (ch + 1) * BK)
        }
        short8v ah[2], al[2], wh[4], wl[4];
#pragma unroll
        for (int fi = 0; fi < 2; ++fi) {
            const float* base = &As[buf][wm + fi * 16 + row16][0];
            const f32x4 v0 = *(const f32x4*)(base + sg0);
            const f32x4 v1 = *(const f32x4*)(base + sg1);
            cvt_hilo(v0, v1, ah[fi], al[fi]);
        }
#pragma unroll
        for (int fj = 0; fj < 4; ++fj) {
            const float* base = &Ws[buf][wn + fj * 16 + row16][0];
            const f32x4 v0 = *(const f32x4*)(base + sg0);
            const f32x4 v1 = *(const f32x4*)(base + sg1);
            cvt_hilo(v0, v1, wh[fj], wl[fj]);
        }
#pragma unroll
        for (int fi = 0; fi < 2; ++fi)
#pragma unroll
            for (int fj = 0; fj < 4; ++fj) {
                acc[fi][fj] = __builtin_amdgcn_mfma_f32_16x16x32_bf16(
                    ah[fi], wh[fj], acc[fi][fj], 0, 0, 0);
                acc[fi][fj] = __builtin_amdgcn_mfma_f32_16x16x32_bf16(
                    ah[fi], wl[fj], acc[fi][fj], 0, 0, 0);
                acc[fi][fj] = __builtin_amdgcn_mfma_f32_16x16x32_bf16(
                    al[fi], wh[fj], acc[fi][fj], 0, 0, 0);
            }
    }
#undef STAGE

    // C/D layout (m89): col = lane&15, row = (lane>>4)*4 + r
#pragma unroll
    for (int fi = 0; fi < 2; ++fi)
#pragma unroll
        for (int fj = 0; fj < 4; ++fj) {
#pragma unroll
            for (int r = 0; r < 4; ++r) {
                const int m = m0 + wm + fi * 16 + kq * 4 + r;
                const int p = wn + fj * 16 + row16;
                qkP[(size_t)m * NP + p] = acc[fi][fj][r];
            }
        }
}

// ---------------- K2: sum partials + bias, neighbor scores, 2-way softmax ----------------
__global__ __launch_bounds__(256) void neighbor_probs(const float* __restrict__ qk0,
                                                      const float* __restrict__ qk1,
                                                      const float* __restrict__ bias,
                                                      float* __restrict__ p0,
                                                      float* __restrict__ p1) {
    const int m = blockIdx.x * 4 + (threadIdx.x >> 6);  // position index m = s*B+b
    const int lane = threadIdx.x & 63;
    const int s = m >> 3;   // / B_DIM
    const int b = m & 7;    // % B_DIM

    const float bq = bias[lane];
    const float bk = bias[PD + lane];
    const size_t oq = (size_t)m * NP + lane;
    const float q = qk0[oq] + qk1[oq] + bq;
    float kn = 0.f, kp = 0.f;
    if (s < S_DIM - 1) {
        const size_t o = (size_t)(m + B_DIM) * NP + PD + lane;
        kn = qk0[o] + qk1[o] + bk;
    }
    if (s > 0) {
        const size_t o = (size_t)(m - B_DIM) * NP + PD + lane;
        kp = qk0[o] + qk1[o] + bk;
    }
    float f = q * kn;   // fwd partial: query[s] . key[s+1]
    float g = q * kp;   // bwd partial: query[s] . key[s-1]
#pragma unroll
    for (int off = 32; off; off >>= 1) {
        f += __shfl_xor(f, off);
        g += __shfl_xor(g, off);
    }
    if (lane == 0) {
        const float s0 = f * (1.f / (float)E_DIM);
        const float s1 = g * (1.f / (float)E_DIM);
        float P0, P1;
        if (s == S_DIM - 1) { P0 = 0.f; P1 = 1.f; }
        else if (s == 0)    { P0 = 1.f; P1 = 0.f; }
        else {
            const float mx = fmaxf(s0, s1);
            const float e0 = __expf(s0 - mx), e1 = __expf(s1 - mx);
            const float inv = 1.f / (e0 + e1);
            P0 = e0 * inv; P1 = e1 * inv;
        }
        p0[b * S_DIM + s] = P0;
        p1[b * S_DIM + s] = P1;
    }
}

// ---------------- K3: combine (flat roll), neighbor_attn out, log, exclusive scan ----------------
__global__ __launch_bounds__(256) void combine_scan(const float* __restrict__ p0,
                                                    const float* __restrict__ p1,
                                                    const float* __restrict__ prior,
                                                    float* __restrict__ out_na,
                                                    float* __restrict__ cs) {
    const int b = blockIdx.x;
    const int tid = threadIdx.x;
    __shared__ float sh[256];

    const int base = b * S_DIM + tid * 8;
    float incl[8];
    float run = 0.f;
#pragma unroll
    for (int u = 0; u < 8; ++u) {
        const int fidx = base + u;
        int nf = fidx + 1;
        if (nf == B_DIM * S_DIM) nf = 0;   // torch .roll on flattened tensor wraps globally
        const float P0 = p0[fidx];
        const float sp = p1[nf];
        const float pr = prior[fidx];
        const float na = pr + (1.f - pr) * sqrtf(P0 * sp + 1e-6f);
        out_na[fidx] = na;
        run += __logf(na);
        incl[u] = run;
    }
    sh[tid] = run;
    __syncthreads();
    for (int off = 1; off < 256; off <<= 1) {
        float v = sh[tid];
        if (tid >= off) v += sh[tid - off];
        __syncthreads();
        sh[tid] = v;
        __syncthreads();
    }
    const float offset = (tid > 0) ? sh[tid - 1] : 0.f;
#pragma unroll
    for (int u = 0; u < 8; ++u) {
        cs[base + u] = offset + ((u > 0) ? incl[u - 1] : 0.f);  // exclusive prefix
    }
}

// ---------------- K4: big output C[b,i,j] = exp(sign*(cs[j]-cs[i])), 0 on diag ----------------
__global__ __launch_bounds__(256) void big_out(const float* __restrict__ cs,
                                               float* __restrict__ out) {
    const int bi = blockIdx.x;          // b*S + i
    const int b = bi >> 11;             // / S_DIM
    const int i = bi & (S_DIM - 1);
    const float ci = cs[b * S_DIM + i];
    const float* crow = cs + (size_t)b * S_DIM;
    float* orow = out + (size_t)bi * S_DIM;
    const int j0 = threadIdx.x * 8;
#pragma unroll
    for (int h = 0; h < 2; ++h) {
        const int j = j0 + h * 4;
        const float4 cj = *(const float4*)&crow[j];
        float4 o;
        {
            const int jj = j + 0; const float m = (jj > i) ? (cj.x - ci) : (ci - cj.x);
            o.x = (jj == i) ? 0.f : __expf(m);
        }
        {
            const int jj = j + 1; const float m = (jj > i) ? (cj.y - ci) : (ci - cj.y);
            o.y = (jj == i) ? 0.f : __expf(m);
        }
        {
            const int jj = j + 2; const float m = (jj > i) ? (cj.z - ci) : (ci - cj.z);
            o.z = (jj == i) ? 0.f : __expf(m);
        }
        {
            const int jj = j + 3; const float m = (jj > i) ? (cj.w - ci) : (ci - cj.w);
            o.w = (jj == i) ? 0.f : __expf(m);
        }
        *(float4*)&orow[j] = o;
    }
}

extern "C" void kernel_launch(void* const* d_in, const int* in_sizes, int n_in,
                              void* d_out, int out_size, void* d_ws, size_t ws_size,
                              hipStream_t stream) {
    const float* context = (const float*)d_in[0];   // (S,B,E) fp32
    const float* prior   = (const float*)d_in[1];   // (B,S) fp32
    const float* W       = (const float*)d_in[2];   // (128,1024) fp32
    const float* bias    = (const float*)d_in[3];   // (128,) fp32
    float* out = (float*)d_out;

    float* qk0 = (float*)d_ws;                         // 16384*128 floats (8 MB)
    float* p0  = qk0 + (size_t)M_TOT * NP;             // 16384 floats
    float* p1  = p0 + M_TOT;                           // 16384 floats
    float* cs  = p1 + M_TOT;                           // 16384 floats
    // second partial lives in d_out's C-region; K4 overwrites it afterwards
    float* qk1 = out;
    float* na_out = out + (size_t)B_DIM * S_DIM * S_DIM;  // second output

    gemm_qk<<<(M_TOT / BM) * 2, 256, 0, stream>>>(context, W, qk0, qk1);
    neighbor_probs<<<M_TOT / 4, 256, 0, stream>>>(qk0, qk1, bias, p0, p1);
    combine_scan<<<B_DIM, 256, 0, stream>>>(p0, p1, prior, na_out, cs);
    big_out<<<M_TOT, 256, 0, stream>>>(cs, out);
}